// Round 4
// baseline (180.322 us; speedup 1.0000x reference)
//
#include <hip/hip_runtime.h>
#include <hip/hip_bf16.h>

typedef unsigned short u16;
typedef unsigned int u32;
typedef __attribute__((ext_vector_type(8))) short short8;
typedef __attribute__((ext_vector_type(4))) float f32x4;
typedef __attribute__((ext_vector_type(16))) float f32x16;
typedef __attribute__((ext_vector_type(4))) u32 u32x4;

__device__ __forceinline__ u16 f2b(float f) {
    __hip_bfloat16 h = __float2bfloat16(f);
    return *reinterpret_cast<u16*>(&h);
}
__device__ __forceinline__ float b2f(u16 u) {
    __hip_bfloat16 h;
    *reinterpret_cast<u16*>(&h) = u;
    return __bfloat162float(h);
}
__device__ __forceinline__ u32 cvtpk(float lo, float hi_) {
    u32 r;
    asm("v_cvt_pk_bf16_f32 %0, %1, %2" : "=v"(r) : "v"(lo), "v"(hi_));
    return r;
}
__device__ __forceinline__ float fexp2(float x) {
    float r;
    asm("v_exp_f32 %0, %1" : "=v"(r) : "v"(x));
    return r;
}
__device__ __forceinline__ void gload16(const void* g, void* l) {
    __builtin_amdgcn_global_load_lds(
        (const __attribute__((address_space(1))) unsigned int*)g,
        (__attribute__((address_space(3))) unsigned int*)l, 16, 0, 0);
}

// ---------------- 1. fp32 -> bf16 convert ----------------
__global__ void convert_kernel(const float* __restrict__ X, const float* __restrict__ W1,
                               const float* __restrict__ W2,
                               u16* __restrict__ Xb, u16* __restrict__ W1b, u16* __restrict__ W2b) {
    int idx = blockIdx.x * 256 + threadIdx.x;   // 1,703,936 total
    const float* src; u16* dst; int off;
    if (idx < 1048576)        { src = X;  dst = Xb;  off = idx; }
    else if (idx < 1441792)   { src = W1; dst = W1b; off = idx - 1048576; }
    else                      { src = W2; dst = W2b; off = idx - 1441792; }
    float4 v = reinterpret_cast<const float4*>(src)[off];
    ushort4 o;
    o.x = f2b(v.x); o.y = f2b(v.y); o.z = f2b(v.z); o.w = f2b(v.w);
    reinterpret_cast<ushort4*>(dst)[off] = o;
}

// ---------------- 2/7. NT GEMM, 64x128 tile, BK=64, double-buffered prefetch ----------------
// C[M][N] = A[M][K] * B[N][K]^T. 4 waves 2x2, wave tile 32x64. 32 MFMA per barrier.
template <typename OUT>
__global__ __launch_bounds__(256) void gemm_bt(const u16* __restrict__ A, const u16* __restrict__ B,
                                               OUT* __restrict__ C, int M, int N, int K) {
    __shared__ u16 As[2][64 * 64];
    __shared__ u16 Bs[2][128 * 64];
    const int tid = threadIdx.x;
    const int lane = tid & 63, wave = tid >> 6;
    const int wm = wave >> 1, wn = wave & 1;
    const int row16 = lane & 15, kgrp = lane >> 4;
    const int bm = blockIdx.x, bn = blockIdx.y;
    const int nk = K >> 6;
    const u16* Abase = A + (size_t)bm * 64 * K;
    const u16* Bbase = B + (size_t)bn * 128 * K;

    f32x4 acc[2][4];
#pragma unroll
    for (int i = 0; i < 2; ++i)
#pragma unroll
        for (int j = 0; j < 4; ++j) acc[i][j] = {0.f, 0.f, 0.f, 0.f};

    auto stage = [&](int buf, int kt) {
#pragma unroll
        for (int it = 0; it < 2; ++it) {   // A: 64 rows x 8 chunks = 512
            int chunk = it * 256 + tid;
            int row = chunk >> 3, c = chunk & 7;
            int cs = c ^ (row & 7);
            gload16(Abase + (size_t)row * K + kt * 64 + cs * 8, &As[buf][chunk * 8]);
        }
#pragma unroll
        for (int it = 0; it < 4; ++it) {   // B: 128 rows x 8 chunks = 1024
            int chunk = it * 256 + tid;
            int row = chunk >> 3, c = chunk & 7;
            int cs = c ^ (row & 7);
            gload16(Bbase + (size_t)row * K + kt * 64 + cs * 8, &Bs[buf][chunk * 8]);
        }
    };

    stage(0, 0);
    __syncthreads();
    for (int kt = 0; kt < nk; ++kt) {
        int cur = kt & 1;
        if (kt + 1 < nk) stage(cur ^ 1, kt + 1);
        short8 af[2][2], bfr[4][2];
#pragma unroll
        for (int mf = 0; mf < 2; ++mf) {
            int r = wm * 32 + mf * 16 + row16;
#pragma unroll
            for (int kk = 0; kk < 2; ++kk)
                af[mf][kk] = *(const short8*)&As[cur][(r * 8 + ((kk * 4 + kgrp) ^ (r & 7))) * 8];
        }
#pragma unroll
        for (int nf = 0; nf < 4; ++nf) {
            int r = wn * 64 + nf * 16 + row16;
#pragma unroll
            for (int kk = 0; kk < 2; ++kk)
                bfr[nf][kk] = *(const short8*)&Bs[cur][(r * 8 + ((kk * 4 + kgrp) ^ (r & 7))) * 8];
        }
        __builtin_amdgcn_s_setprio(1);
#pragma unroll
        for (int kk = 0; kk < 2; ++kk)
#pragma unroll
            for (int mf = 0; mf < 2; ++mf)
#pragma unroll
                for (int nf = 0; nf < 4; ++nf)
                    acc[mf][nf] = __builtin_amdgcn_mfma_f32_16x16x32_bf16(af[mf][kk], bfr[nf][kk], acc[mf][nf], 0, 0, 0);
        __builtin_amdgcn_s_setprio(0);
        __syncthreads();
    }
#pragma unroll
    for (int mf = 0; mf < 2; ++mf)
#pragma unroll
        for (int r = 0; r < 4; ++r) {
            int row = bm * 64 + wm * 32 + mf * 16 + kgrp * 4 + r;
#pragma unroll
            for (int nf = 0; nf < 4; ++nf) {
                int col = bn * 128 + wn * 64 + nf * 16 + row16;
                float v = acc[mf][nf][r];
                if constexpr (sizeof(OUT) == 2) C[(size_t)row * N + col] = f2b(v);
                else                            C[(size_t)row * N + col] = v;
            }
        }
}

// ---------------- 3. RoPE + relayout (Q, K only) ----------------
// Q scale folds 1/sqrt(64) AND log2(e): 0.125 * 1.44269504089 = 0.18033688
__global__ void rope_kernel(const u16* __restrict__ qkv, const float* __restrict__ cosb,
                            const float* __restrict__ sinb, u16* __restrict__ Qa,
                            u16* __restrict__ Ka) {
    int idx = blockIdx.x * 256 + threadIdx.x;    // 2,621,440 total
    if (idx < 2097152) {                         // Q
        int d = idx & 31, h = (idx >> 5) & 15, m = idx >> 9;
        int s = m & 2047, b = m >> 11;
        const u16* src = qkv + (size_t)m * 1536 + h * 64 + d;
        float q1 = b2f(src[0]), q2 = b2f(src[32]);
        float c = cosb[s * 64 + d], sn = sinb[s * 64 + d];
        u16* dst = Qa + ((size_t)(b * 16 + h) * 2048 + s) * 64 + d;
        dst[0]  = f2b((q1 * c - q2 * sn) * 0.18033688f);
        dst[32] = f2b((q2 * c + q1 * sn) * 0.18033688f);
    } else {                                     // K
        int t = idx - 2097152;
        int d = t & 31, kh = (t >> 5) & 3, m = t >> 7;
        int s = m & 2047, b = m >> 11;
        const u16* src = qkv + (size_t)m * 1536 + (16 + kh) * 64 + d;
        float q1 = b2f(src[0]), q2 = b2f(src[32]);
        float c = cosb[s * 64 + d], sn = sinb[s * 64 + d];
        u16* dst = Ka + ((size_t)(b * 4 + kh) * 2048 + s) * 64 + d;
        dst[0]  = f2b(q1 * c - q2 * sn);
        dst[32] = f2b(q2 * c + q1 * sn);
    }
}

// ---------------- 4. V transpose: qkv -> Vt[b][kh][d=64][s=2048] ----------------
__global__ __launch_bounds__(256) void vtrans_kernel(const u16* __restrict__ qkv, u16* __restrict__ Vt) {
    __shared__ u16 T[64 * 71];
    const int tid = threadIdx.x;
    const int sblk = blockIdx.x, kh = blockIdx.y, b = blockIdx.z;
    const u16* src = qkv + (size_t)(b * 2048 + sblk * 64) * 1536 + 1280 + kh * 64;
#pragma unroll
    for (int it = 0; it < 2; ++it) {
        int u = it * 256 + tid;
        int s = u >> 3, c = u & 7;
        short8 v = *(const short8*)(src + (size_t)s * 1536 + c * 8);
#pragma unroll
        for (int i = 0; i < 8; ++i)
            T[(c * 8 + i) * 71 + s] = (u16)v[i];
    }
    __syncthreads();
    u16* dst = Vt + (size_t)(b * 4 + kh) * 64 * 2048 + sblk * 64;
#pragma unroll
    for (int it = 0; it < 2; ++it) {
        int u = it * 256 + tid;
        int d = u >> 3, s0 = (u & 7) * 8;
        short8 o;
#pragma unroll
        for (int i = 0; i < 8; ++i) o[i] = (short)T[d * 71 + s0 + i];
        *(short8*)(dst + (size_t)d * 2048 + s0) = o;
    }
}

// ---------------- 5. Flash attention, split-KV 2-way ----------------
// grid (16 qt, 16 h, 4 z) with z = kvs*2 + b. Each block: 16 KV tiles.
// Writes UNNORMALIZED partial O (bf16) into Opart (= d_out scratch) and partial l (f32).
__global__ __launch_bounds__(256) void attn_kernel(const u16* __restrict__ Qa,
                                                   const u16* __restrict__ Ka,
                                                   const u16* __restrict__ Vt,
                                                   u16* __restrict__ Opart,
                                                   float* __restrict__ lpart) {
    __shared__ u16 Ks[2][64 * 64];
    __shared__ u16 Vs[2][64 * 64];
    const int tid = threadIdx.x, lane = tid & 63, wave = tid >> 6;
    const int q32 = lane & 31, hi = lane >> 5;
    const int qt = blockIdx.x, h = blockIdx.y, z = blockIdx.z;
    const int b = z & 1, kvs = z >> 1;
    const int kh = h >> 2;
    const u16* Qp = Qa + ((size_t)(b * 16 + h) * 2048 + qt * 128 + wave * 32) * 64;
    const u16* Kp = Ka + (size_t)(b * 4 + kh) * 2048 * 64;
    const u16* Vp = Vt + (size_t)(b * 4 + kh) * 64 * 2048;

    short8 qf[4];
#pragma unroll
    for (int dt = 0; dt < 4; ++dt)
        qf[dt] = *(const short8*)(Qp + q32 * 64 + dt * 16 + hi * 8);

    f32x16 oacc[2];
#pragma unroll
    for (int i = 0; i < 2; ++i)
#pragma unroll
        for (int r = 0; r < 16; ++r) oacc[i][r] = 0.f;
    float lpx = 0.f, lpy = 0.f;

    auto stageKV = [&](int buf, int kvt) {
#pragma unroll
        for (int it = 0; it < 2; ++it) {
            int chunk = it * 256 + tid;
            int row = chunk >> 3, c = chunk & 7;
            gload16(Kp + (size_t)(kvt * 64 + row) * 64 + ((c ^ (row & 7)) * 8), &Ks[buf][chunk * 8]);
        }
#pragma unroll
        for (int it = 0; it < 2; ++it) {
            int chunk = it * 256 + tid;
            int row = chunk >> 3, c = chunk & 7;
            gload16(Vp + (size_t)row * 2048 + kvt * 64 + ((c ^ (row & 7)) * 8), &Vs[buf][chunk * 8]);
        }
    };

    const int kv0 = kvs * 16;
    stageKV(0, kv0);
    __syncthreads();
    for (int i = 0; i < 16; ++i) {
        const int cur = i & 1;
        if (i + 1 < 16) stageKV(cur ^ 1, kv0 + i + 1);

        f32x16 S[2];
#pragma unroll
        for (int j = 0; j < 2; ++j)
#pragma unroll
            for (int r = 0; r < 16; ++r) S[j][r] = 0.f;
        __builtin_amdgcn_s_setprio(1);
#pragma unroll
        for (int kt2 = 0; kt2 < 2; ++kt2) {
            int krow = kt2 * 32 + q32;
#pragma unroll
            for (int dt = 0; dt < 4; ++dt) {
                short8 kf = *(const short8*)&Ks[cur][(krow * 8 + ((dt * 2 + hi) ^ (krow & 7))) * 8];
                S[kt2] = __builtin_amdgcn_mfma_f32_32x32x16_bf16(kf, qf[dt], S[kt2], 0, 0, 0);
            }
        }
        __builtin_amdgcn_s_setprio(0);

#pragma unroll
        for (int kt2 = 0; kt2 < 2; ++kt2)
#pragma unroll
            for (int r = 0; r < 16; r += 2) {
                float p0 = fexp2(S[kt2][r]);
                float p1 = fexp2(S[kt2][r + 1]);
                S[kt2][r] = p0; S[kt2][r + 1] = p1;
                lpx += p0; lpy += p1;
            }

        __builtin_amdgcn_s_setprio(1);
#pragma unroll
        for (int kc = 0; kc < 4; ++kc) {
            const int kt2 = kc >> 1, R = (kc & 1) * 8;
            u32 a0 = cvtpk(S[kt2][R + 0], S[kt2][R + 1]);
            u32 b0 = cvtpk(S[kt2][R + 4], S[kt2][R + 5]);
            asm("v_permlane32_swap_b32 %0, %1" : "+v"(a0), "+v"(b0));
            u32 a1 = cvtpk(S[kt2][R + 2], S[kt2][R + 3]);
            u32 b1 = cvtpk(S[kt2][R + 6], S[kt2][R + 7]);
            asm("v_permlane32_swap_b32 %0, %1" : "+v"(a1), "+v"(b1));
            u32x4 pw; pw[0] = a0; pw[1] = a1; pw[2] = b0; pw[3] = b1;
            short8 pf = __builtin_bit_cast(short8, pw);
#pragma unroll
            for (int dt2 = 0; dt2 < 2; ++dt2) {
                int vrow = dt2 * 32 + q32;
                short8 vf = *(const short8*)&Vs[cur][(vrow * 8 + ((kc * 2 + hi) ^ (vrow & 7))) * 8];
                oacc[dt2] = __builtin_amdgcn_mfma_f32_32x32x16_bf16(vf, pf, oacc[dt2], 0, 0, 0);
            }
        }
        __builtin_amdgcn_s_setprio(0);
        __syncthreads();
    }

    const int qrow = qt * 128 + wave * 32 + q32;
    float lp = lpx + lpy;
    float l = lp + __shfl_xor(lp, 32);
    if (hi == 0) lpart[((size_t)z * 16 + h) * 2048 + qrow] = l;
    const size_t pbase = (((size_t)z * 16 + h) * 2048 + qrow) * 64;
#pragma unroll
    for (int dt2 = 0; dt2 < 2; ++dt2)
#pragma unroll
        for (int rq = 0; rq < 4; ++rq) {
            ushort4 o;
            o.x = f2b(oacc[dt2][rq * 4 + 0]);
            o.y = f2b(oacc[dt2][rq * 4 + 1]);
            o.z = f2b(oacc[dt2][rq * 4 + 2]);
            o.w = f2b(oacc[dt2][rq * 4 + 3]);
            *(ushort4*)&Opart[pbase + dt2 * 32 + rq * 8 + hi * 4] = o;
        }
}

// ---------------- 6. Combine partials -> attnb[m][h*64+d] bf16 ----------------
__global__ void combine_kernel(const u16* __restrict__ Opart, const float* __restrict__ lpart,
                               u16* __restrict__ attnb) {
    int t = blockIdx.x * 256 + threadIdx.x;   // 1,048,576
    int d4 = t & 15, q = (t >> 4) & 2047, h = (t >> 15) & 15, b = t >> 19;
    size_t i1 = (((size_t)b * 16 + h) * 2048 + q) * 64 + d4 * 4;
    ushort4 o1 = *(const ushort4*)&Opart[i1];
    ushort4 o2 = *(const ushort4*)&Opart[i1 + 4194304];
    size_t li = ((size_t)b * 16 + h) * 2048 + q;
    float inv = 1.f / (lpart[li] + lpart[li + 65536]);
    ushort4 o;
    o.x = f2b((b2f(o1.x) + b2f(o2.x)) * inv);
    o.y = f2b((b2f(o1.y) + b2f(o2.y)) * inv);
    o.z = f2b((b2f(o1.z) + b2f(o2.z)) * inv);
    o.w = f2b((b2f(o1.w) + b2f(o2.w)) * inv);
    *(ushort4*)&attnb[((size_t)(b * 2048 + q)) * 1024 + h * 64 + d4 * 4] = o;
}

// ---------------- launcher ----------------
extern "C" void kernel_launch(void* const* d_in, const int* in_sizes, int n_in,
                              void* d_out, int out_size, void* d_ws, size_t ws_size,
                              hipStream_t stream) {
    const float* X    = (const float*)d_in[0];
    const float* cosb = (const float*)d_in[1];
    const float* sinb = (const float*)d_in[2];
    const float* Wqkv = (const float*)d_in[3];
    const float* Wo   = (const float*)d_in[4];
    float* out = (float*)d_out;
    char* ws = (char*)d_ws;

    u16* Xbf    = (u16*)(ws);                    // 8,388,608 B (aliased attnb after gemm1)
    u16* Wqkvbf = (u16*)(ws + 8388608);          // 3,145,728 B
    u16* Wobf   = (u16*)(ws + 11534336);         // 2,097,152 B
    u16* QKV    = (u16*)(ws + 13631488);         // 12,582,912 B (lpart aliases after vtrans)
    u16* Qa     = (u16*)(ws + 26214400);         // 8,388,608 B
    u16* Ka     = (u16*)(ws + 34603008);         // 2,097,152 B
    u16* Vt     = (u16*)(ws + 36700160);         // 2,097,152 B -> total 38,797,312 B
    u16* attnb  = Xbf;
    float* lpart = (float*)QKV;                  // 524,288 B, QKV dead after vtrans
    u16* Opart  = (u16*)d_out;                   // 16,777,216 B scratch; gemm2 overwrites last

    convert_kernel<<<6656, 256, 0, stream>>>(X, Wqkv, Wo, Xbf, Wqkvbf, Wobf);
    gemm_bt<u16><<<dim3(64, 12), 256, 0, stream>>>(Xbf, Wqkvbf, QKV, 4096, 1536, 1024);
    rope_kernel<<<10240, 256, 0, stream>>>(QKV, cosb, sinb, Qa, Ka);
    vtrans_kernel<<<dim3(32, 4, 2), 256, 0, stream>>>(QKV, Vt);
    attn_kernel<<<dim3(16, 16, 4), 256, 0, stream>>>(Qa, Ka, Vt, Opart, lpart);
    combine_kernel<<<4096, 256, 0, stream>>>(Opart, lpart, attnb);
    gemm_bt<float><<<dim3(64, 8), 256, 0, stream>>>(attnb, Wobf, out, 4096, 1024, 1024);
}

// Round 5
// 176.270 us; speedup vs baseline: 1.0230x; 1.0230x over previous
//
#include <hip/hip_runtime.h>
#include <hip/hip_bf16.h>

typedef unsigned short u16;
typedef unsigned int u32;
typedef __attribute__((ext_vector_type(8))) short short8;
typedef __attribute__((ext_vector_type(4))) float f32x4;
typedef __attribute__((ext_vector_type(16))) float f32x16;
typedef __attribute__((ext_vector_type(4))) u32 u32x4;

__device__ __forceinline__ u16 f2b(float f) {
    __hip_bfloat16 h = __float2bfloat16(f);
    return *reinterpret_cast<u16*>(&h);
}
__device__ __forceinline__ float b2f(u16 u) {
    __hip_bfloat16 h;
    *reinterpret_cast<u16*>(&h) = u;
    return __bfloat162float(h);
}
__device__ __forceinline__ u32 cvtpk(float lo, float hi_) {
    u32 r;
    asm("v_cvt_pk_bf16_f32 %0, %1, %2" : "=v"(r) : "v"(lo), "v"(hi_));
    return r;
}
// Full-rate-VALU 2^x (avoids the shared transcendental pipe).
// n = rndne(x); f = x-n in [-0.5,0.5]; 2^f Taylor deg-3 (rel err ~6e-4); ldexp.
__device__ __forceinline__ float fexp2p(float x) {
    float nf = __builtin_rintf(x);
    float f = x - nf;
    float p = __builtin_fmaf(f, 0.05550411f, 0.24022651f);
    p = __builtin_fmaf(f, p, 0.69314718f);
    p = __builtin_fmaf(f, p, 1.0f);
    int n = (int)nf;
    float r;
    asm("v_ldexp_f32 %0, %1, %2" : "=v"(r) : "v"(p), "v"(n));
    return r;
}
__device__ __forceinline__ void gload16(const void* g, void* l) {
    __builtin_amdgcn_global_load_lds(
        (const __attribute__((address_space(1))) unsigned int*)g,
        (__attribute__((address_space(3))) unsigned int*)l, 16, 0, 0);
}

// ---------------- 1. fp32 -> bf16 convert ----------------
__global__ void convert_kernel(const float* __restrict__ X, const float* __restrict__ W1,
                               const float* __restrict__ W2,
                               u16* __restrict__ Xb, u16* __restrict__ W1b, u16* __restrict__ W2b) {
    int idx = blockIdx.x * 256 + threadIdx.x;   // 1,703,936 total
    const float* src; u16* dst; int off;
    if (idx < 1048576)        { src = X;  dst = Xb;  off = idx; }
    else if (idx < 1441792)   { src = W1; dst = W1b; off = idx - 1048576; }
    else                      { src = W2; dst = W2b; off = idx - 1441792; }
    float4 v = reinterpret_cast<const float4*>(src)[off];
    ushort4 o;
    o.x = f2b(v.x); o.y = f2b(v.y); o.z = f2b(v.z); o.w = f2b(v.w);
    reinterpret_cast<ushort4*>(dst)[off] = o;
}

// ---------------- 2/6. NT GEMM, 64x128 tile, BK=64, double-buffered prefetch ----------------
template <typename OUT>
__global__ __launch_bounds__(256) void gemm_bt(const u16* __restrict__ A, const u16* __restrict__ B,
                                               OUT* __restrict__ C, int M, int N, int K) {
    __shared__ u16 As[2][64 * 64];
    __shared__ u16 Bs[2][128 * 64];
    const int tid = threadIdx.x;
    const int lane = tid & 63, wave = tid >> 6;
    const int wm = wave >> 1, wn = wave & 1;
    const int row16 = lane & 15, kgrp = lane >> 4;
    const int bm = blockIdx.x, bn = blockIdx.y;
    const int nk = K >> 6;
    const u16* Abase = A + (size_t)bm * 64 * K;
    const u16* Bbase = B + (size_t)bn * 128 * K;

    f32x4 acc[2][4];
#pragma unroll
    for (int i = 0; i < 2; ++i)
#pragma unroll
        for (int j = 0; j < 4; ++j) acc[i][j] = {0.f, 0.f, 0.f, 0.f};

    auto stage = [&](int buf, int kt) {
#pragma unroll
        for (int it = 0; it < 2; ++it) {   // A: 64 rows x 8 chunks = 512
            int chunk = it * 256 + tid;
            int row = chunk >> 3, c = chunk & 7;
            int cs = c ^ (row & 7);
            gload16(Abase + (size_t)row * K + kt * 64 + cs * 8, &As[buf][chunk * 8]);
        }
#pragma unroll
        for (int it = 0; it < 4; ++it) {   // B: 128 rows x 8 chunks = 1024
            int chunk = it * 256 + tid;
            int row = chunk >> 3, c = chunk & 7;
            int cs = c ^ (row & 7);
            gload16(Bbase + (size_t)row * K + kt * 64 + cs * 8, &Bs[buf][chunk * 8]);
        }
    };

    stage(0, 0);
    __syncthreads();
    for (int kt = 0; kt < nk; ++kt) {
        int cur = kt & 1;
        if (kt + 1 < nk) stage(cur ^ 1, kt + 1);
        short8 af[2][2], bfr[4][2];
#pragma unroll
        for (int mf = 0; mf < 2; ++mf) {
            int r = wm * 32 + mf * 16 + row16;
#pragma unroll
            for (int kk = 0; kk < 2; ++kk)
                af[mf][kk] = *(const short8*)&As[cur][(r * 8 + ((kk * 4 + kgrp) ^ (r & 7))) * 8];
        }
#pragma unroll
        for (int nf = 0; nf < 4; ++nf) {
            int r = wn * 64 + nf * 16 + row16;
#pragma unroll
            for (int kk = 0; kk < 2; ++kk)
                bfr[nf][kk] = *(const short8*)&Bs[cur][(r * 8 + ((kk * 4 + kgrp) ^ (r & 7))) * 8];
        }
        __builtin_amdgcn_s_setprio(1);
#pragma unroll
        for (int kk = 0; kk < 2; ++kk)
#pragma unroll
            for (int mf = 0; mf < 2; ++mf)
#pragma unroll
                for (int nf = 0; nf < 4; ++nf)
                    acc[mf][nf] = __builtin_amdgcn_mfma_f32_16x16x32_bf16(af[mf][kk], bfr[nf][kk], acc[mf][nf], 0, 0, 0);
        __builtin_amdgcn_s_setprio(0);
        __syncthreads();
    }
#pragma unroll
    for (int mf = 0; mf < 2; ++mf)
#pragma unroll
        for (int r = 0; r < 4; ++r) {
            int row = bm * 64 + wm * 32 + mf * 16 + kgrp * 4 + r;
#pragma unroll
            for (int nf = 0; nf < 4; ++nf) {
                int col = bn * 128 + wn * 64 + nf * 16 + row16;
                float v = acc[mf][nf][r];
                if constexpr (sizeof(OUT) == 2) C[(size_t)row * N + col] = f2b(v);
                else                            C[(size_t)row * N + col] = v;
            }
        }
}

// ---------------- 3. RoPE + relayout (Q, K only) ----------------
// Q scale folds 1/sqrt(64) AND log2(e): 0.125 * 1.44269504089 = 0.18033688
__global__ void rope_kernel(const u16* __restrict__ qkv, const float* __restrict__ cosb,
                            const float* __restrict__ sinb, u16* __restrict__ Qa,
                            u16* __restrict__ Ka) {
    int idx = blockIdx.x * 256 + threadIdx.x;    // 2,621,440 total
    if (idx < 2097152) {                         // Q
        int d = idx & 31, h = (idx >> 5) & 15, m = idx >> 9;
        int s = m & 2047, b = m >> 11;
        const u16* src = qkv + (size_t)m * 1536 + h * 64 + d;
        float q1 = b2f(src[0]), q2 = b2f(src[32]);
        float c = cosb[s * 64 + d], sn = sinb[s * 64 + d];
        u16* dst = Qa + ((size_t)(b * 16 + h) * 2048 + s) * 64 + d;
        dst[0]  = f2b((q1 * c - q2 * sn) * 0.18033688f);
        dst[32] = f2b((q2 * c + q1 * sn) * 0.18033688f);
    } else {                                     // K
        int t = idx - 2097152;
        int d = t & 31, kh = (t >> 5) & 3, m = t >> 7;
        int s = m & 2047, b = m >> 11;
        const u16* src = qkv + (size_t)m * 1536 + (16 + kh) * 64 + d;
        float q1 = b2f(src[0]), q2 = b2f(src[32]);
        float c = cosb[s * 64 + d], sn = sinb[s * 64 + d];
        u16* dst = Ka + ((size_t)(b * 4 + kh) * 2048 + s) * 64 + d;
        dst[0]  = f2b(q1 * c - q2 * sn);
        dst[32] = f2b(q2 * c + q1 * sn);
    }
}

// ---------------- 4. V transpose: qkv -> Vt[b][kh][d=64][s=2048] ----------------
__global__ __launch_bounds__(256) void vtrans_kernel(const u16* __restrict__ qkv, u16* __restrict__ Vt) {
    __shared__ u16 T[64 * 71];
    const int tid = threadIdx.x;
    const int sblk = blockIdx.x, kh = blockIdx.y, b = blockIdx.z;
    const u16* src = qkv + (size_t)(b * 2048 + sblk * 64) * 1536 + 1280 + kh * 64;
#pragma unroll
    for (int it = 0; it < 2; ++it) {
        int u = it * 256 + tid;
        int s = u >> 3, c = u & 7;
        short8 v = *(const short8*)(src + (size_t)s * 1536 + c * 8);
#pragma unroll
        for (int i = 0; i < 8; ++i)
            T[(c * 8 + i) * 71 + s] = (u16)v[i];
    }
    __syncthreads();
    u16* dst = Vt + (size_t)(b * 4 + kh) * 64 * 2048 + sblk * 64;
#pragma unroll
    for (int it = 0; it < 2; ++it) {
        int u = it * 256 + tid;
        int d = u >> 3, s0 = (u & 7) * 8;
        short8 o;
#pragma unroll
        for (int i = 0; i < 8; ++i) o[i] = (short)T[d * 71 + s0 + i];
        *(short8*)(dst + (size_t)d * 2048 + s0) = o;
    }
}

// ---------------- 5. Flash attention, swapped-QK^T 32x32, poly-exp2 softmax ----------------
__global__ __launch_bounds__(256) void attn_kernel(const u16* __restrict__ Qa,
                                                   const u16* __restrict__ Ka,
                                                   const u16* __restrict__ Vt,
                                                   u16* __restrict__ Ob) {
    __shared__ u16 Ks[2][64 * 64];
    __shared__ u16 Vs[2][64 * 64];
    const int tid = threadIdx.x, lane = tid & 63, wave = tid >> 6;
    const int q32 = lane & 31, hi = lane >> 5;
    const int qt = blockIdx.x, h = blockIdx.y, b = blockIdx.z;
    const int kh = h >> 2;
    const u16* Qp = Qa + ((size_t)(b * 16 + h) * 2048 + qt * 128 + wave * 32) * 64;
    const u16* Kp = Ka + (size_t)(b * 4 + kh) * 2048 * 64;
    const u16* Vp = Vt + (size_t)(b * 4 + kh) * 64 * 2048;

    short8 qf[4];
#pragma unroll
    for (int dt = 0; dt < 4; ++dt)
        qf[dt] = *(const short8*)(Qp + q32 * 64 + dt * 16 + hi * 8);

    f32x16 oacc[2];
#pragma unroll
    for (int i = 0; i < 2; ++i)
#pragma unroll
        for (int r = 0; r < 16; ++r) oacc[i][r] = 0.f;
    float lpx = 0.f, lpy = 0.f;

    auto stageKV = [&](int buf, int kvt) {
#pragma unroll
        for (int it = 0; it < 2; ++it) {
            int chunk = it * 256 + tid;
            int row = chunk >> 3, c = chunk & 7;
            gload16(Kp + (size_t)(kvt * 64 + row) * 64 + ((c ^ (row & 7)) * 8), &Ks[buf][chunk * 8]);
        }
#pragma unroll
        for (int it = 0; it < 2; ++it) {
            int chunk = it * 256 + tid;
            int row = chunk >> 3, c = chunk & 7;
            gload16(Vp + (size_t)row * 2048 + kvt * 64 + ((c ^ (row & 7)) * 8), &Vs[buf][chunk * 8]);
        }
    };

    stageKV(0, 0);
    __syncthreads();
    for (int kvt = 0; kvt < 32; ++kvt) {
        const int cur = kvt & 1;
        if (kvt + 1 < 32) stageKV(cur ^ 1, kvt + 1);

        f32x16 S[2];
#pragma unroll
        for (int j = 0; j < 2; ++j)
#pragma unroll
            for (int r = 0; r < 16; ++r) S[j][r] = 0.f;
        __builtin_amdgcn_s_setprio(1);
#pragma unroll
        for (int kt2 = 0; kt2 < 2; ++kt2) {
            int krow = kt2 * 32 + q32;
#pragma unroll
            for (int dt = 0; dt < 4; ++dt) {
                short8 kf = *(const short8*)&Ks[cur][(krow * 8 + ((dt * 2 + hi) ^ (krow & 7))) * 8];
                S[kt2] = __builtin_amdgcn_mfma_f32_32x32x16_bf16(kf, qf[dt], S[kt2], 0, 0, 0);
            }
        }
        __builtin_amdgcn_s_setprio(0);

        // p = 2^s via full-rate polynomial (trans-pipe bypass)
#pragma unroll
        for (int kt2 = 0; kt2 < 2; ++kt2)
#pragma unroll
            for (int r = 0; r < 16; r += 2) {
                float p0 = fexp2p(S[kt2][r]);
                float p1 = fexp2p(S[kt2][r + 1]);
                S[kt2][r] = p0; S[kt2][r + 1] = p1;
                lpx += p0; lpy += p1;
            }

        __builtin_amdgcn_s_setprio(1);
#pragma unroll
        for (int kc = 0; kc < 4; ++kc) {
            const int kt2 = kc >> 1, R = (kc & 1) * 8;
            u32 a0 = cvtpk(S[kt2][R + 0], S[kt2][R + 1]);
            u32 b0 = cvtpk(S[kt2][R + 4], S[kt2][R + 5]);
            asm("v_permlane32_swap_b32 %0, %1" : "+v"(a0), "+v"(b0));
            u32 a1 = cvtpk(S[kt2][R + 2], S[kt2][R + 3]);
            u32 b1 = cvtpk(S[kt2][R + 6], S[kt2][R + 7]);
            asm("v_permlane32_swap_b32 %0, %1" : "+v"(a1), "+v"(b1));
            u32x4 pw; pw[0] = a0; pw[1] = a1; pw[2] = b0; pw[3] = b1;
            short8 pf = __builtin_bit_cast(short8, pw);
#pragma unroll
            for (int dt2 = 0; dt2 < 2; ++dt2) {
                int vrow = dt2 * 32 + q32;
                short8 vf = *(const short8*)&Vs[cur][(vrow * 8 + ((kc * 2 + hi) ^ (vrow & 7))) * 8];
                oacc[dt2] = __builtin_amdgcn_mfma_f32_32x32x16_bf16(vf, pf, oacc[dt2], 0, 0, 0);
            }
        }
        __builtin_amdgcn_s_setprio(0);
        __syncthreads();
    }

    float lpart = lpx + lpy;
    float l = lpart + __shfl_xor(lpart, 32);
    float inv = 1.f / l;
    const size_t mbase = ((size_t)(b * 2048 + qt * 128 + wave * 32 + q32)) * 1024 + h * 64;
#pragma unroll
    for (int dt2 = 0; dt2 < 2; ++dt2)
#pragma unroll
        for (int rq = 0; rq < 4; ++rq) {
            ushort4 o;
            o.x = f2b(oacc[dt2][rq * 4 + 0] * inv);
            o.y = f2b(oacc[dt2][rq * 4 + 1] * inv);
            o.z = f2b(oacc[dt2][rq * 4 + 2] * inv);
            o.w = f2b(oacc[dt2][rq * 4 + 3] * inv);
            *(ushort4*)&Ob[mbase + dt2 * 32 + rq * 8 + hi * 4] = o;
        }
}

// ---------------- launcher ----------------
extern "C" void kernel_launch(void* const* d_in, const int* in_sizes, int n_in,
                              void* d_out, int out_size, void* d_ws, size_t ws_size,
                              hipStream_t stream) {
    const float* X    = (const float*)d_in[0];
    const float* cosb = (const float*)d_in[1];
    const float* sinb = (const float*)d_in[2];
    const float* Wqkv = (const float*)d_in[3];
    const float* Wo   = (const float*)d_in[4];
    float* out = (float*)d_out;
    char* ws = (char*)d_ws;

    u16* Xbf    = (u16*)(ws);                    // 8,388,608 B (aliased attnb after gemm1)
    u16* Wqkvbf = (u16*)(ws + 8388608);          // 3,145,728 B
    u16* Wobf   = (u16*)(ws + 11534336);         // 2,097,152 B
    u16* QKV    = (u16*)(ws + 13631488);         // 12,582,912 B
    u16* Qa     = (u16*)(ws + 26214400);         // 8,388,608 B
    u16* Ka     = (u16*)(ws + 34603008);         // 2,097,152 B
    u16* Vt     = (u16*)(ws + 36700160);         // 2,097,152 B -> total 38,797,312 B
    u16* attnb  = Xbf;

    convert_kernel<<<6656, 256, 0, stream>>>(X, Wqkv, Wo, Xbf, Wqkvbf, Wobf);
    gemm_bt<u16><<<dim3(64, 12), 256, 0, stream>>>(Xbf, Wqkvbf, QKV, 4096, 1536, 1024);
    rope_kernel<<<10240, 256, 0, stream>>>(QKV, cosb, sinb, Qa, Ka);
    vtrans_kernel<<<dim3(32, 4, 2), 256, 0, stream>>>(QKV, Vt);
    attn_kernel<<<dim3(16, 16, 2), 256, 0, stream>>>(Qa, Ka, Vt, attnb);
    gemm_bt<float><<<dim3(64, 8), 256, 0, stream>>>(attnb, Wobf, out, 4096, 1024, 1024);
}

// Round 7
// 171.032 us; speedup vs baseline: 1.0543x; 1.0306x over previous
//
#include <hip/hip_runtime.h>
#include <hip/hip_bf16.h>

typedef unsigned short u16;
typedef unsigned int u32;
typedef __attribute__((ext_vector_type(8))) short short8;
typedef __attribute__((ext_vector_type(4))) float f32x4;
typedef __attribute__((ext_vector_type(16))) float f32x16;
typedef __attribute__((ext_vector_type(4))) u32 u32x4;

__device__ __forceinline__ u16 f2b(float f) {
    __hip_bfloat16 h = __float2bfloat16(f);
    return *reinterpret_cast<u16*>(&h);
}
__device__ __forceinline__ float b2f(u16 u) {
    __hip_bfloat16 h;
    *reinterpret_cast<u16*>(&h) = u;
    return __bfloat162float(h);
}
__device__ __forceinline__ u32 cvtpk(float lo, float hi_) {
    u32 r;
    asm("v_cvt_pk_bf16_f32 %0, %1, %2" : "=v"(r) : "v"(lo), "v"(hi_));
    return r;
}
__device__ __forceinline__ float fexp2(float x) {
    float r;
    asm("v_exp_f32 %0, %1" : "=v"(r) : "v"(x));
    return r;
}
__device__ __forceinline__ void gload16(const void* g, void* l) {
    __builtin_amdgcn_global_load_lds(
        (const __attribute__((address_space(1))) unsigned int*)g,
        (__attribute__((address_space(3))) unsigned int*)l, 16, 0, 0);
}

// ---------------- 1. fp32 -> bf16 convert ----------------
__global__ void convert_kernel(const float* __restrict__ X, const float* __restrict__ W1,
                               const float* __restrict__ W2,
                               u16* __restrict__ Xb, u16* __restrict__ W1b, u16* __restrict__ W2b) {
    int idx = blockIdx.x * 256 + threadIdx.x;   // 1,703,936 total
    const float* src; u16* dst; int off;
    if (idx < 1048576)        { src = X;  dst = Xb;  off = idx; }
    else if (idx < 1441792)   { src = W1; dst = W1b; off = idx - 1048576; }
    else                      { src = W2; dst = W2b; off = idx - 1441792; }
    float4 v = reinterpret_cast<const float4*>(src)[off];
    ushort4 o;
    o.x = f2b(v.x); o.y = f2b(v.y); o.z = f2b(v.z); o.w = f2b(v.w);
    reinterpret_cast<ushort4*>(dst)[off] = o;
}

// ---------------- 2/6. NT GEMM, 64x128 tile, BK=64, double-buffered prefetch ----------------
template <typename OUT>
__global__ __launch_bounds__(256) void gemm_bt(const u16* __restrict__ A, const u16* __restrict__ B,
                                               OUT* __restrict__ C, int M, int N, int K) {
    __shared__ u16 As[2][64 * 64];
    __shared__ u16 Bs[2][128 * 64];
    const int tid = threadIdx.x;
    const int lane = tid & 63, wave = tid >> 6;
    const int wm = wave >> 1, wn = wave & 1;
    const int row16 = lane & 15, kgrp = lane >> 4;
    const int bm = blockIdx.x, bn = blockIdx.y;
    const int nk = K >> 6;
    const u16* Abase = A + (size_t)bm * 64 * K;
    const u16* Bbase = B + (size_t)bn * 128 * K;

    f32x4 acc[2][4];
#pragma unroll
    for (int i = 0; i < 2; ++i)
#pragma unroll
        for (int j = 0; j < 4; ++j) acc[i][j] = {0.f, 0.f, 0.f, 0.f};

    auto stage = [&](int buf, int kt) {
#pragma unroll
        for (int it = 0; it < 2; ++it) {   // A: 64 rows x 8 chunks = 512
            int chunk = it * 256 + tid;
            int row = chunk >> 3, c = chunk & 7;
            int cs = c ^ (row & 7);
            gload16(Abase + (size_t)row * K + kt * 64 + cs * 8, &As[buf][chunk * 8]);
        }
#pragma unroll
        for (int it = 0; it < 4; ++it) {   // B: 128 rows x 8 chunks = 1024
            int chunk = it * 256 + tid;
            int row = chunk >> 3, c = chunk & 7;
            int cs = c ^ (row & 7);
            gload16(Bbase + (size_t)row * K + kt * 64 + cs * 8, &Bs[buf][chunk * 8]);
        }
    };

    stage(0, 0);
    __syncthreads();
    for (int kt = 0; kt < nk; ++kt) {
        int cur = kt & 1;
        if (kt + 1 < nk) stage(cur ^ 1, kt + 1);
        short8 af[2][2], bfr[4][2];
#pragma unroll
        for (int mf = 0; mf < 2; ++mf) {
            int r = wm * 32 + mf * 16 + row16;
#pragma unroll
            for (int kk = 0; kk < 2; ++kk)
                af[mf][kk] = *(const short8*)&As[cur][(r * 8 + ((kk * 4 + kgrp) ^ (r & 7))) * 8];
        }
#pragma unroll
        for (int nf = 0; nf < 4; ++nf) {
            int r = wn * 64 + nf * 16 + row16;
#pragma unroll
            for (int kk = 0; kk < 2; ++kk)
                bfr[nf][kk] = *(const short8*)&Bs[cur][(r * 8 + ((kk * 4 + kgrp) ^ (r & 7))) * 8];
        }
        __builtin_amdgcn_s_setprio(1);
#pragma unroll
        for (int kk = 0; kk < 2; ++kk)
#pragma unroll
            for (int mf = 0; mf < 2; ++mf)
#pragma unroll
                for (int nf = 0; nf < 4; ++nf)
                    acc[mf][nf] = __builtin_amdgcn_mfma_f32_16x16x32_bf16(af[mf][kk], bfr[nf][kk], acc[mf][nf], 0, 0, 0);
        __builtin_amdgcn_s_setprio(0);
        __syncthreads();
    }
#pragma unroll
    for (int mf = 0; mf < 2; ++mf)
#pragma unroll
        for (int r = 0; r < 4; ++r) {
            int row = bm * 64 + wm * 32 + mf * 16 + kgrp * 4 + r;
#pragma unroll
            for (int nf = 0; nf < 4; ++nf) {
                int col = bn * 128 + wn * 64 + nf * 16 + row16;
                float v = acc[mf][nf][r];
                if constexpr (sizeof(OUT) == 2) C[(size_t)row * N + col] = f2b(v);
                else                            C[(size_t)row * N + col] = v;
            }
        }
}

// ---------------- 3. RoPE + relayout (Q, K only) ----------------
// Q scale folds 1/sqrt(64) AND log2(e): 0.125 * 1.44269504089 = 0.18033688
__global__ void rope_kernel(const u16* __restrict__ qkv, const float* __restrict__ cosb,
                            const float* __restrict__ sinb, u16* __restrict__ Qa,
                            u16* __restrict__ Ka) {
    int idx = blockIdx.x * 256 + threadIdx.x;    // 2,621,440 total
    if (idx < 2097152) {                         // Q
        int d = idx & 31, h = (idx >> 5) & 15, m = idx >> 9;
        int s = m & 2047, b = m >> 11;
        const u16* src = qkv + (size_t)m * 1536 + h * 64 + d;
        float q1 = b2f(src[0]), q2 = b2f(src[32]);
        float c = cosb[s * 64 + d], sn = sinb[s * 64 + d];
        u16* dst = Qa + ((size_t)(b * 16 + h) * 2048 + s) * 64 + d;
        dst[0]  = f2b((q1 * c - q2 * sn) * 0.18033688f);
        dst[32] = f2b((q2 * c + q1 * sn) * 0.18033688f);
    } else {                                     // K
        int t = idx - 2097152;
        int d = t & 31, kh = (t >> 5) & 3, m = t >> 7;
        int s = m & 2047, b = m >> 11;
        const u16* src = qkv + (size_t)m * 1536 + (16 + kh) * 64 + d;
        float q1 = b2f(src[0]), q2 = b2f(src[32]);
        float c = cosb[s * 64 + d], sn = sinb[s * 64 + d];
        u16* dst = Ka + ((size_t)(b * 4 + kh) * 2048 + s) * 64 + d;
        dst[0]  = f2b(q1 * c - q2 * sn);
        dst[32] = f2b(q2 * c + q1 * sn);
    }
}

// ---------------- 4. V transpose: qkv -> Vt[b][kh][d=64][s=2048] ----------------
__global__ __launch_bounds__(256) void vtrans_kernel(const u16* __restrict__ qkv, u16* __restrict__ Vt) {
    __shared__ u16 T[64 * 71];
    const int tid = threadIdx.x;
    const int sblk = blockIdx.x, kh = blockIdx.y, b = blockIdx.z;
    const u16* src = qkv + (size_t)(b * 2048 + sblk * 64) * 1536 + 1280 + kh * 64;
#pragma unroll
    for (int it = 0; it < 2; ++it) {
        int u = it * 256 + tid;
        int s = u >> 3, c = u & 7;
        short8 v = *(const short8*)(src + (size_t)s * 1536 + c * 8);
#pragma unroll
        for (int i = 0; i < 8; ++i)
            T[(c * 8 + i) * 71 + s] = (u16)v[i];
    }
    __syncthreads();
    u16* dst = Vt + (size_t)(b * 4 + kh) * 64 * 2048 + sblk * 64;
#pragma unroll
    for (int it = 0; it < 2; ++it) {
        int u = it * 256 + tid;
        int d = u >> 3, s0 = (u & 7) * 8;
        short8 o;
#pragma unroll
        for (int i = 0; i < 8; ++i) o[i] = (short)T[d * 71 + s0 + i];
        *(short8*)(dst + (size_t)d * 2048 + s0) = o;
    }
}

// ---------------- 5. Flash attention: 3-buffer ring, counted vmcnt (T3+T4) ----------------
// Loads issued 2 tiles ahead; steady-state wait vmcnt(8) (2 tiles in flight), never 0.
// Raw s_barrier pairs: [vmcnt -> barrier -> compute -> lgkmcnt(0) -> barrier].
__global__ __launch_bounds__(256) void attn_kernel(const u16* __restrict__ Qa,
                                                   const u16* __restrict__ Ka,
                                                   const u16* __restrict__ Vt,
                                                   u16* __restrict__ Ob) {
    __shared__ u16 Ks[3][64 * 64];
    __shared__ u16 Vs[3][64 * 64];
    const int tid = threadIdx.x, lane = tid & 63, wave = tid >> 6;
    const int q32 = lane & 31, hi = lane >> 5;
    const int qt = blockIdx.x, h = blockIdx.y, b = blockIdx.z;
    const int kh = h >> 2;
    const u16* Qp = Qa + ((size_t)(b * 16 + h) * 2048 + qt * 128 + wave * 32) * 64;
    const u16* Kp = Ka + (size_t)(b * 4 + kh) * 2048 * 64;
    const u16* Vp = Vt + (size_t)(b * 4 + kh) * 64 * 2048;

    short8 qf[4];
#pragma unroll
    for (int dt = 0; dt < 4; ++dt)
        qf[dt] = *(const short8*)(Qp + q32 * 64 + dt * 16 + hi * 8);

    f32x16 oacc[2];
#pragma unroll
    for (int i = 0; i < 2; ++i)
#pragma unroll
        for (int r = 0; r < 16; ++r) oacc[i][r] = 0.f;
    float lpx = 0.f, lpy = 0.f;

    // 4 vmem ops per thread per tile (2 K + 2 V)
    auto stageKV = [&](int buf, int kvt) {
#pragma unroll
        for (int it = 0; it < 2; ++it) {
            int chunk = it * 256 + tid;
            int row = chunk >> 3, c = chunk & 7;
            gload16(Kp + (size_t)(kvt * 64 + row) * 64 + ((c ^ (row & 7)) * 8), &Ks[buf][chunk * 8]);
        }
#pragma unroll
        for (int it = 0; it < 2; ++it) {
            int chunk = it * 256 + tid;
            int row = chunk >> 3, c = chunk & 7;
            gload16(Vp + (size_t)row * 2048 + kvt * 64 + ((c ^ (row & 7)) * 8), &Vs[buf][chunk * 8]);
        }
    };

    stageKV(0, 0);
    stageKV(1, 1);
    int cur = 0;
    for (int kvt = 0; kvt < 32; ++kvt) {
        int stg = cur + 2; if (stg >= 3) stg -= 3;
        if (kvt + 2 < 32) stageKV(stg, kvt + 2);
        // wait for tile kvt's 4 loads (oldest) to land; keep up to 2 tiles in flight
        if (kvt < 30)       asm volatile("s_waitcnt vmcnt(8)" ::: "memory");
        else if (kvt == 30) asm volatile("s_waitcnt vmcnt(4)" ::: "memory");
        else                asm volatile("s_waitcnt vmcnt(0)" ::: "memory");
        __builtin_amdgcn_s_barrier();

        // S^T = K_tile x Q^T : C[k'][q]
        f32x16 S[2];
#pragma unroll
        for (int j = 0; j < 2; ++j)
#pragma unroll
            for (int r = 0; r < 16; ++r) S[j][r] = 0.f;
        __builtin_amdgcn_s_setprio(1);
#pragma unroll
        for (int kt2 = 0; kt2 < 2; ++kt2) {
            int krow = kt2 * 32 + q32;
#pragma unroll
            for (int dt = 0; dt < 4; ++dt) {
                short8 kf = *(const short8*)&Ks[cur][(krow * 8 + ((dt * 2 + hi) ^ (krow & 7))) * 8];
                S[kt2] = __builtin_amdgcn_mfma_f32_32x32x16_bf16(kf, qf[dt], S[kt2], 0, 0, 0);
            }
        }
        __builtin_amdgcn_s_setprio(0);

        // p = 2^s (log2e folded into Q scale)
#pragma unroll
        for (int kt2 = 0; kt2 < 2; ++kt2)
#pragma unroll
            for (int r = 0; r < 16; r += 2) {
                float p0 = fexp2(S[kt2][r]);
                float p1 = fexp2(S[kt2][r + 1]);
                S[kt2][r] = p0; S[kt2][r + 1] = p1;
                lpx += p0; lpy += p1;
            }

        // P -> bf16 B-frags (cvt_pk + permlane32_swap), O^T += V^T P^T
        __builtin_amdgcn_s_setprio(1);
#pragma unroll
        for (int kc = 0; kc < 4; ++kc) {
            const int kt2 = kc >> 1, R = (kc & 1) * 8;
            u32 a0 = cvtpk(S[kt2][R + 0], S[kt2][R + 1]);
            u32 b0 = cvtpk(S[kt2][R + 4], S[kt2][R + 5]);
            asm("v_permlane32_swap_b32 %0, %1" : "+v"(a0), "+v"(b0));
            u32 a1 = cvtpk(S[kt2][R + 2], S[kt2][R + 3]);
            u32 b1 = cvtpk(S[kt2][R + 6], S[kt2][R + 7]);
            asm("v_permlane32_swap_b32 %0, %1" : "+v"(a1), "+v"(b1));
            u32x4 pw; pw[0] = a0; pw[1] = a1; pw[2] = b0; pw[3] = b1;
            short8 pf = __builtin_bit_cast(short8, pw);
#pragma unroll
            for (int dt2 = 0; dt2 < 2; ++dt2) {
                int vrow = dt2 * 32 + q32;
                short8 vf = *(const short8*)&Vs[cur][(vrow * 8 + ((kc * 2 + hi) ^ (vrow & 7))) * 8];
                oacc[dt2] = __builtin_amdgcn_mfma_f32_32x32x16_bf16(vf, pf, oacc[dt2], 0, 0, 0);
            }
        }
        __builtin_amdgcn_s_setprio(0);

        // all waves done reading buf[cur] before iter kvt+1 overwrites it
        asm volatile("s_waitcnt lgkmcnt(0)" ::: "memory");
        __builtin_amdgcn_s_barrier();
        cur += 1; if (cur >= 3) cur -= 3;
    }

    float lpart = lpx + lpy;
    float l = lpart + __shfl_xor(lpart, 32);
    float inv = 1.f / l;
    const size_t mbase = ((size_t)(b * 2048 + qt * 128 + wave * 32 + q32)) * 1024 + h * 64;
#pragma unroll
    for (int dt2 = 0; dt2 < 2; ++dt2)
#pragma unroll
        for (int rq = 0; rq < 4; ++rq) {
            ushort4 o;
            o.x = f2b(oacc[dt2][rq * 4 + 0] * inv);
            o.y = f2b(oacc[dt2][rq * 4 + 1] * inv);
            o.z = f2b(oacc[dt2][rq * 4 + 2] * inv);
            o.w = f2b(oacc[dt2][rq * 4 + 3] * inv);
            *(ushort4*)&Ob[mbase + dt2 * 32 + rq * 8 + hi * 4] = o;
        }
}

// ---------------- launcher ----------------
extern "C" void kernel_launch(void* const* d_in, const int* in_sizes, int n_in,
                              void* d_out, int out_size, void* d_ws, size_t ws_size,
                              hipStream_t stream) {
    const float* X    = (const float*)d_in[0];
    const float* cosb = (const float*)d_in[1];
    const float* sinb = (const float*)d_in[2];
    const float* Wqkv = (const float*)d_in[3];
    const float* Wo   = (const float*)d_in[4];
    float* out = (float*)d_out;
    char* ws = (char*)d_ws;

    u16* Xbf    = (u16*)(ws);                    // 8,388,608 B (aliased attnb after gemm1)
    u16* Wqkvbf = (u16*)(ws + 8388608);          // 3,145,728 B
    u16* Wobf   = (u16*)(ws + 11534336);         // 2,097,152 B
    u16* QKV    = (u16*)(ws + 13631488);         // 12,582,912 B
    u16* Qa     = (u16*)(ws + 26214400);         // 8,388,608 B
    u16* Ka     = (u16*)(ws + 34603008);         // 2,097,152 B
    u16* Vt     = (u16*)(ws + 36700160);         // 2,097,152 B -> total 38,797,312 B
    u16* attnb  = Xbf;

    convert_kernel<<<6656, 256, 0, stream>>>(X, Wqkv, Wo, Xbf, Wqkvbf, Wobf);
    gemm_bt<u16><<<dim3(64, 12), 256, 0, stream>>>(Xbf, Wqkvbf, QKV, 4096, 1536, 1024);
    rope_kernel<<<10240, 256, 0, stream>>>(QKV, cosb, sinb, Qa, Ka);
    vtrans_kernel<<<dim3(32, 4, 2), 256, 0, stream>>>(QKV, Vt);
    attn_kernel<<<dim3(16, 16, 2), 256, 0, stream>>>(Qa, Ka, Vt, attnb);
    gemm_bt<float><<<dim3(64, 8), 256, 0, stream>>>(attnb, Wobf, out, 4096, 1024, 1024);
}

// Round 8
// 166.615 us; speedup vs baseline: 1.0823x; 1.0265x over previous
//
#include <hip/hip_runtime.h>
#include <hip/hip_bf16.h>

typedef unsigned short u16;
typedef unsigned int u32;
typedef __attribute__((ext_vector_type(8))) short short8;
typedef __attribute__((ext_vector_type(4))) float f32x4;
typedef __attribute__((ext_vector_type(16))) float f32x16;
typedef __attribute__((ext_vector_type(4))) u32 u32x4;

__device__ __forceinline__ u16 f2b(float f) {
    __hip_bfloat16 h = __float2bfloat16(f);
    return *reinterpret_cast<u16*>(&h);
}
__device__ __forceinline__ float b2f(u16 u) {
    __hip_bfloat16 h;
    *reinterpret_cast<u16*>(&h) = u;
    return __bfloat162float(h);
}
__device__ __forceinline__ u32 cvtpk(float lo, float hi_) {
    u32 r;
    asm("v_cvt_pk_bf16_f32 %0, %1, %2" : "=v"(r) : "v"(lo), "v"(hi_));
    return r;
}
__device__ __forceinline__ float fexp2(float x) {
    float r;
    asm("v_exp_f32 %0, %1" : "=v"(r) : "v"(x));
    return r;
}
__device__ __forceinline__ void gload16(const void* g, void* l) {
    __builtin_amdgcn_global_load_lds(
        (const __attribute__((address_space(1))) unsigned int*)g,
        (__attribute__((address_space(3))) unsigned int*)l, 16, 0, 0);
}

// ---------------- 1. fp32 -> bf16 convert ----------------
__global__ void convert_kernel(const float* __restrict__ X, const float* __restrict__ W1,
                               const float* __restrict__ W2,
                               u16* __restrict__ Xb, u16* __restrict__ W1b, u16* __restrict__ W2b) {
    int idx = blockIdx.x * 256 + threadIdx.x;   // 1,703,936 total
    const float* src; u16* dst; int off;
    if (idx < 1048576)        { src = X;  dst = Xb;  off = idx; }
    else if (idx < 1441792)   { src = W1; dst = W1b; off = idx - 1048576; }
    else                      { src = W2; dst = W2b; off = idx - 1441792; }
    float4 v = reinterpret_cast<const float4*>(src)[off];
    ushort4 o;
    o.x = f2b(v.x); o.y = f2b(v.y); o.z = f2b(v.z); o.w = f2b(v.w);
    reinterpret_cast<ushort4*>(dst)[off] = o;
}

// ---------------- 2/6. NT GEMM, 64x128 tile, BK=64, dbuf prefetch, ptr-increment staging --
template <typename OUT>
__global__ __launch_bounds__(256, 3) void gemm_bt(const u16* __restrict__ A, const u16* __restrict__ B,
                                                  OUT* __restrict__ C, int M, int N, int K) {
    __shared__ u16 As[2][64 * 64];
    __shared__ u16 Bs[2][128 * 64];
    const int tid = threadIdx.x;
    const int lane = tid & 63, wave = tid >> 6;
    const int wm = wave >> 1, wn = wave & 1;
    const int row16 = lane & 15, kgrp = lane >> 4;
    const int bm = blockIdx.x, bn = blockIdx.y;
    const int nk = K >> 6;

    // per-thread staging pointers (advance +64 per K-step). Swizzle invariant under row+32.
    const int r0 = tid >> 3, c0s = ((tid & 7) ^ (r0 & 7)) * 8;
    const u16* aSrc = A + (size_t)(bm * 64 + r0) * K + c0s;
    const u16* bSrc = B + (size_t)(bn * 128 + r0) * K + c0s;
    u16* const ad0 = &As[0][tid * 8];
    u16* const ad1 = &As[0][(tid + 256) * 8];
    u16* const bd0 = &Bs[0][tid * 8];
    u16* const bd1 = &Bs[0][(tid + 256) * 8];
    u16* const bd2 = &Bs[0][(tid + 512) * 8];
    u16* const bd3 = &Bs[0][(tid + 768) * 8];
    const size_t aK32 = (size_t)32 * K;

    f32x4 acc[2][4];
#pragma unroll
    for (int i = 0; i < 2; ++i)
#pragma unroll
        for (int j = 0; j < 4; ++j) acc[i][j] = {0.f, 0.f, 0.f, 0.f};

    auto stage = [&](int buf) {
        int lo = buf * 4096;      // 64*64 elements per A buffer
        int lob = buf * 8192;     // 128*64 per B buffer
        gload16(aSrc, ad0 + lo);
        gload16(aSrc + aK32, ad1 + lo);
        gload16(bSrc, bd0 + lob);
        gload16(bSrc + aK32, bd1 + lob);
        gload16(bSrc + 2 * aK32, bd2 + lob);
        gload16(bSrc + 3 * aK32, bd3 + lob);
        aSrc += 64; bSrc += 64;
    };

    stage(0);
    __syncthreads();
    for (int kt = 0; kt < nk; ++kt) {
        int cur = kt & 1;
        if (kt + 1 < nk) stage(cur ^ 1);
        short8 af[2][2], bfr[4][2];
#pragma unroll
        for (int mf = 0; mf < 2; ++mf) {
            int r = wm * 32 + mf * 16 + row16;
#pragma unroll
            for (int kk = 0; kk < 2; ++kk)
                af[mf][kk] = *(const short8*)&As[cur][(r * 8 + ((kk * 4 + kgrp) ^ (r & 7))) * 8];
        }
#pragma unroll
        for (int nf = 0; nf < 4; ++nf) {
            int r = wn * 64 + nf * 16 + row16;
#pragma unroll
            for (int kk = 0; kk < 2; ++kk)
                bfr[nf][kk] = *(const short8*)&Bs[cur][(r * 8 + ((kk * 4 + kgrp) ^ (r & 7))) * 8];
        }
        __builtin_amdgcn_s_setprio(1);
#pragma unroll
        for (int kk = 0; kk < 2; ++kk)
#pragma unroll
            for (int mf = 0; mf < 2; ++mf)
#pragma unroll
                for (int nf = 0; nf < 4; ++nf)
                    acc[mf][nf] = __builtin_amdgcn_mfma_f32_16x16x32_bf16(af[mf][kk], bfr[nf][kk], acc[mf][nf], 0, 0, 0);
        __builtin_amdgcn_s_setprio(0);
        __syncthreads();
    }
#pragma unroll
    for (int mf = 0; mf < 2; ++mf)
#pragma unroll
        for (int r = 0; r < 4; ++r) {
            int row = bm * 64 + wm * 32 + mf * 16 + kgrp * 4 + r;
#pragma unroll
            for (int nf = 0; nf < 4; ++nf) {
                int col = bn * 128 + wn * 64 + nf * 16 + row16;
                float v = acc[mf][nf][r];
                if constexpr (sizeof(OUT) == 2) C[(size_t)row * N + col] = f2b(v);
                else                            C[(size_t)row * N + col] = v;
            }
        }
}

// ---------------- 3. RoPE + relayout (Q, K only) ----------------
// Q scale folds 1/sqrt(64) AND log2(e): 0.125 * 1.44269504089 = 0.18033688
__global__ void rope_kernel(const u16* __restrict__ qkv, const float* __restrict__ cosb,
                            const float* __restrict__ sinb, u16* __restrict__ Qa,
                            u16* __restrict__ Ka) {
    int idx = blockIdx.x * 256 + threadIdx.x;    // 2,621,440 total
    if (idx < 2097152) {                         // Q
        int d = idx & 31, h = (idx >> 5) & 15, m = idx >> 9;
        int s = m & 2047, b = m >> 11;
        const u16* src = qkv + (size_t)m * 1536 + h * 64 + d;
        float q1 = b2f(src[0]), q2 = b2f(src[32]);
        float c = cosb[s * 64 + d], sn = sinb[s * 64 + d];
        u16* dst = Qa + ((size_t)(b * 16 + h) * 2048 + s) * 64 + d;
        dst[0]  = f2b((q1 * c - q2 * sn) * 0.18033688f);
        dst[32] = f2b((q2 * c + q1 * sn) * 0.18033688f);
    } else {                                     // K
        int t = idx - 2097152;
        int d = t & 31, kh = (t >> 5) & 3, m = t >> 7;
        int s = m & 2047, b = m >> 11;
        const u16* src = qkv + (size_t)m * 1536 + (16 + kh) * 64 + d;
        float q1 = b2f(src[0]), q2 = b2f(src[32]);
        float c = cosb[s * 64 + d], sn = sinb[s * 64 + d];
        u16* dst = Ka + ((size_t)(b * 4 + kh) * 2048 + s) * 64 + d;
        dst[0]  = f2b(q1 * c - q2 * sn);
        dst[32] = f2b(q2 * c + q1 * sn);
    }
}

// ---------------- 4. V transpose: qkv -> Vt[b][kh][d=64][s=2048] ----------------
__global__ __launch_bounds__(256) void vtrans_kernel(const u16* __restrict__ qkv, u16* __restrict__ Vt) {
    __shared__ u16 T[64 * 71];
    const int tid = threadIdx.x;
    const int sblk = blockIdx.x, kh = blockIdx.y, b = blockIdx.z;
    const u16* src = qkv + (size_t)(b * 2048 + sblk * 64) * 1536 + 1280 + kh * 64;
#pragma unroll
    for (int it = 0; it < 2; ++it) {
        int u = it * 256 + tid;
        int s = u >> 3, c = u & 7;
        short8 v = *(const short8*)(src + (size_t)s * 1536 + c * 8);
#pragma unroll
        for (int i = 0; i < 8; ++i)
            T[(c * 8 + i) * 71 + s] = (u16)v[i];
    }
    __syncthreads();
    u16* dst = Vt + (size_t)(b * 4 + kh) * 64 * 2048 + sblk * 64;
#pragma unroll
    for (int it = 0; it < 2; ++it) {
        int u = it * 256 + tid;
        int d = u >> 3, s0 = (u & 7) * 8;
        short8 o;
#pragma unroll
        for (int i = 0; i < 8; ++i) o[i] = (short)T[d * 71 + s0 + i];
        *(short8*)(dst + (size_t)d * 2048 + s0) = o;
    }
}

// ---------------- 5. Flash attention: swapped-QK^T 32x32, dbuf, reg-budgeted ----------------
// __launch_bounds__(256,2): 256-VGPR budget so S/oacc live in arch VGPRs (no AGPR shuttling)
// and LDS-read offsets get hoisted. Staging via pointer increments.
__global__ __launch_bounds__(256, 2) void attn_kernel(const u16* __restrict__ Qa,
                                                      const u16* __restrict__ Ka,
                                                      const u16* __restrict__ Vt,
                                                      u16* __restrict__ Ob) {
    __shared__ u16 Ks[2][64 * 64];
    __shared__ u16 Vs[2][64 * 64];
    const int tid = threadIdx.x, lane = tid & 63, wave = tid >> 6;
    const int q32 = lane & 31, hi = lane >> 5;
    const int qt = blockIdx.x, h = blockIdx.y, b = blockIdx.z;
    const int kh = h >> 2;
    const u16* Qp = Qa + ((size_t)(b * 16 + h) * 2048 + qt * 128 + wave * 32) * 64;

    // staging pointers: K advances +4096 elems/tile, V +64 elems/tile.
    const int r0 = tid >> 3, c0s = ((tid & 7) ^ (r0 & 7)) * 8;   // row+32 keeps (row&7)
    const u16* kSrc = Ka + (size_t)(b * 4 + kh) * 2048 * 64 + (size_t)r0 * 64 + c0s;
    const u16* vSrc = Vt + (size_t)(b * 4 + kh) * 64 * 2048 + (size_t)r0 * 2048 + c0s;
    u16* const kd0 = &Ks[0][tid * 8];
    u16* const kd1 = &Ks[0][(tid + 256) * 8];
    u16* const vd0 = &Vs[0][tid * 8];
    u16* const vd1 = &Vs[0][(tid + 256) * 8];

    short8 qf[4];
#pragma unroll
    for (int dt = 0; dt < 4; ++dt)
        qf[dt] = *(const short8*)(Qp + q32 * 64 + dt * 16 + hi * 8);

    f32x16 oacc[2];
#pragma unroll
    for (int i = 0; i < 2; ++i)
#pragma unroll
        for (int r = 0; r < 16; ++r) oacc[i][r] = 0.f;
    float lpx = 0.f, lpy = 0.f;

    auto stageKV = [&](int buf) {
        int lo = buf * 4096;
        gload16(kSrc,           kd0 + lo);
        gload16(kSrc + 32 * 64, kd1 + lo);
        gload16(vSrc,             vd0 + lo);
        gload16(vSrc + 32 * 2048, vd1 + lo);
        kSrc += 4096; vSrc += 64;
    };

    stageKV(0);
    __syncthreads();
    for (int kvt = 0; kvt < 32; ++kvt) {
        const int cur = kvt & 1;
        if (kvt + 1 < 32) stageKV(cur ^ 1);

        // S^T = K_tile x Q^T : C[k'][q]
        f32x16 S[2];
#pragma unroll
        for (int j = 0; j < 2; ++j)
#pragma unroll
            for (int r = 0; r < 16; ++r) S[j][r] = 0.f;
        __builtin_amdgcn_s_setprio(1);
#pragma unroll
        for (int kt2 = 0; kt2 < 2; ++kt2) {
            int krow = kt2 * 32 + q32;
#pragma unroll
            for (int dt = 0; dt < 4; ++dt) {
                short8 kf = *(const short8*)&Ks[cur][(krow * 8 + ((dt * 2 + hi) ^ (krow & 7))) * 8];
                S[kt2] = __builtin_amdgcn_mfma_f32_32x32x16_bf16(kf, qf[dt], S[kt2], 0, 0, 0);
            }
        }
        __builtin_amdgcn_s_setprio(0);

        // p = 2^s (log2e folded into Q scale)
#pragma unroll
        for (int kt2 = 0; kt2 < 2; ++kt2)
#pragma unroll
            for (int r = 0; r < 16; r += 2) {
                float p0 = fexp2(S[kt2][r]);
                float p1 = fexp2(S[kt2][r + 1]);
                S[kt2][r] = p0; S[kt2][r + 1] = p1;
                lpx += p0; lpy += p1;
            }

        // P -> bf16 B-frags (cvt_pk + permlane32_swap), O^T += V^T P^T
        __builtin_amdgcn_s_setprio(1);
#pragma unroll
        for (int kc = 0; kc < 4; ++kc) {
            const int kt2 = kc >> 1, R = (kc & 1) * 8;
            u32 a0 = cvtpk(S[kt2][R + 0], S[kt2][R + 1]);
            u32 b0 = cvtpk(S[kt2][R + 4], S[kt2][R + 5]);
            asm("v_permlane32_swap_b32 %0, %1" : "+v"(a0), "+v"(b0));
            u32 a1 = cvtpk(S[kt2][R + 2], S[kt2][R + 3]);
            u32 b1 = cvtpk(S[kt2][R + 6], S[kt2][R + 7]);
            asm("v_permlane32_swap_b32 %0, %1" : "+v"(a1), "+v"(b1));
            u32x4 pw; pw[0] = a0; pw[1] = a1; pw[2] = b0; pw[3] = b1;
            short8 pf = __builtin_bit_cast(short8, pw);
#pragma unroll
            for (int dt2 = 0; dt2 < 2; ++dt2) {
                int vrow = dt2 * 32 + q32;
                short8 vf = *(const short8*)&Vs[cur][(vrow * 8 + ((kc * 2 + hi) ^ (vrow & 7))) * 8];
                oacc[dt2] = __builtin_amdgcn_mfma_f32_32x32x16_bf16(vf, pf, oacc[dt2], 0, 0, 0);
            }
        }
        __builtin_amdgcn_s_setprio(0);
        __syncthreads();
    }

    float lpart = lpx + lpy;
    float l = lpart + __shfl_xor(lpart, 32);
    float inv = 1.f / l;
    const size_t mbase = ((size_t)(b * 2048 + qt * 128 + wave * 32 + q32)) * 1024 + h * 64;
#pragma unroll
    for (int dt2 = 0; dt2 < 2; ++dt2)
#pragma unroll
        for (int rq = 0; rq < 4; ++rq) {
            ushort4 o;
            o.x = f2b(oacc[dt2][rq * 4 + 0] * inv);
            o.y = f2b(oacc[dt2][rq * 4 + 1] * inv);
            o.z = f2b(oacc[dt2][rq * 4 + 2] * inv);
            o.w = f2b(oacc[dt2][rq * 4 + 3] * inv);
            *(ushort4*)&Ob[mbase + dt2 * 32 + rq * 8 + hi * 4] = o;
        }
}

// ---------------- launcher ----------------
extern "C" void kernel_launch(void* const* d_in, const int* in_sizes, int n_in,
                              void* d_out, int out_size, void* d_ws, size_t ws_size,
                              hipStream_t stream) {
    const float* X    = (const float*)d_in[0];
    const float* cosb = (const float*)d_in[1];
    const float* sinb = (const float*)d_in[2];
    const float* Wqkv = (const float*)d_in[3];
    const float* Wo   = (const float*)d_in[4];
    float* out = (float*)d_out;
    char* ws = (char*)d_ws;

    u16* Xbf    = (u16*)(ws);                    // 8,388,608 B (aliased attnb after gemm1)
    u16* Wqkvbf = (u16*)(ws + 8388608);          // 3,145,728 B
    u16* Wobf   = (u16*)(ws + 11534336);         // 2,097,152 B
    u16* QKV    = (u16*)(ws + 13631488);         // 12,582,912 B
    u16* Qa     = (u16*)(ws + 26214400);         // 8,388,608 B
    u16* Ka     = (u16*)(ws + 34603008);         // 2,097,152 B
    u16* Vt     = (u16*)(ws + 36700160);         // 2,097,152 B -> total 38,797,312 B
    u16* attnb  = Xbf;

    convert_kernel<<<6656, 256, 0, stream>>>(X, Wqkv, Wo, Xbf, Wqkvbf, Wobf);
    gemm_bt<u16><<<dim3(64, 12), 256, 0, stream>>>(Xbf, Wqkvbf, QKV, 4096, 1536, 1024);
    rope_kernel<<<10240, 256, 0, stream>>>(QKV, cosb, sinb, Qa, Ka);
    vtrans_kernel<<<dim3(32, 4, 2), 256, 0, stream>>>(QKV, Vt);
    attn_kernel<<<dim3(16, 16, 2), 256, 0, stream>>>(Qa, Ka, Vt, attnb);
    gemm_bt<float><<<dim3(64, 8), 256, 0, stream>>>(attnb, Wobf, out, 4096, 1024, 1024);
}

// Round 9
// 157.005 us; speedup vs baseline: 1.1485x; 1.0612x over previous
//
#include <hip/hip_runtime.h>
#include <hip/hip_bf16.h>

typedef unsigned short u16;
typedef unsigned int u32;
typedef __attribute__((ext_vector_type(8))) short short8;
typedef __attribute__((ext_vector_type(4))) float f32x4;
typedef __attribute__((ext_vector_type(16))) float f32x16;
typedef __attribute__((ext_vector_type(4))) u32 u32x4;

__device__ __forceinline__ u16 f2b(float f) {
    __hip_bfloat16 h = __float2bfloat16(f);
    return *reinterpret_cast<u16*>(&h);
}
__device__ __forceinline__ float b2f(u16 u) {
    __hip_bfloat16 h;
    *reinterpret_cast<u16*>(&h) = u;
    return __bfloat162float(h);
}
__device__ __forceinline__ u32 cvtpk(float lo, float hi_) {
    u32 r;
    asm("v_cvt_pk_bf16_f32 %0, %1, %2" : "=v"(r) : "v"(lo), "v"(hi_));
    return r;
}
__device__ __forceinline__ float fexp2(float x) {
    float r;
    asm("v_exp_f32 %0, %1" : "=v"(r) : "v"(x));
    return r;
}
__device__ __forceinline__ void gload16(const void* g, void* l) {
    __builtin_amdgcn_global_load_lds(
        (const __attribute__((address_space(1))) unsigned int*)g,
        (__attribute__((address_space(3))) unsigned int*)l, 16, 0, 0);
}

// ---------------- 1. fp32 -> bf16 convert ----------------
__global__ void convert_kernel(const float* __restrict__ X, const float* __restrict__ W1,
                               const float* __restrict__ W2,
                               u16* __restrict__ Xb, u16* __restrict__ W1b, u16* __restrict__ W2b) {
    int idx = blockIdx.x * 256 + threadIdx.x;   // 1,703,936 total
    const float* src; u16* dst; int off;
    if (idx < 1048576)        { src = X;  dst = Xb;  off = idx; }
    else if (idx < 1441792)   { src = W1; dst = W1b; off = idx - 1048576; }
    else                      { src = W2; dst = W2b; off = idx - 1441792; }
    float4 v = reinterpret_cast<const float4*>(src)[off];
    ushort4 o;
    o.x = f2b(v.x); o.y = f2b(v.y); o.z = f2b(v.z); o.w = f2b(v.w);
    reinterpret_cast<ushort4*>(dst)[off] = o;
}

// ---------------- 2. QKV GEMM with fused RoPE epilogue ----------------
// A = Xbf[4096][1024], B = Wqkvbf[1536][1024]; 64x128 tile, BK=64, dbuf.
// Epilogue: bn 0..7 -> RoPE*scale -> Qa ; bn 8..9 -> RoPE -> Ka ; bn 10..11 -> Vtmp[m][256].
// RoPE pairs (d, d+32) = (nf, nf+2) within each thread. cos[s][d]=cos[s][d%32].
__global__ __launch_bounds__(256, 3) void gemm_qkv(const u16* __restrict__ A, const u16* __restrict__ B,
                                                   const float* __restrict__ cosb, const float* __restrict__ sinb,
                                                   u16* __restrict__ Qa, u16* __restrict__ Ka,
                                                   u16* __restrict__ Vtmp) {
    __shared__ u16 As[2][64 * 64];
    __shared__ u16 Bs[2][128 * 64];
    const int tid = threadIdx.x;
    const int lane = tid & 63, wave = tid >> 6;
    const int wm = wave >> 1, wn = wave & 1;
    const int row16 = lane & 15, kgrp = lane >> 4;
    const int bm = blockIdx.x, bn = blockIdx.y;
    const int K = 1024;

    const int r0 = tid >> 3, c0s = ((tid & 7) ^ (r0 & 7)) * 8;
    const u16* aSrc = A + (size_t)(bm * 64 + r0) * K + c0s;
    const u16* bSrc = B + (size_t)(bn * 128 + r0) * K + c0s;
    u16* const ad0 = &As[0][tid * 8];
    u16* const ad1 = &As[0][(tid + 256) * 8];
    u16* const bd0 = &Bs[0][tid * 8];
    u16* const bd1 = &Bs[0][(tid + 256) * 8];
    u16* const bd2 = &Bs[0][(tid + 512) * 8];
    u16* const bd3 = &Bs[0][(tid + 768) * 8];
    const size_t aK32 = (size_t)32 * K;

    f32x4 acc[2][4];
#pragma unroll
    for (int i = 0; i < 2; ++i)
#pragma unroll
        for (int j = 0; j < 4; ++j) acc[i][j] = {0.f, 0.f, 0.f, 0.f};

    auto stage = [&](int buf) {
        int lo = buf * 4096;
        int lob = buf * 8192;
        gload16(aSrc, ad0 + lo);
        gload16(aSrc + aK32, ad1 + lo);
        gload16(bSrc, bd0 + lob);
        gload16(bSrc + aK32, bd1 + lob);
        gload16(bSrc + 2 * aK32, bd2 + lob);
        gload16(bSrc + 3 * aK32, bd3 + lob);
        aSrc += 64; bSrc += 64;
    };

    stage(0);
    __syncthreads();
    for (int kt = 0; kt < 16; ++kt) {
        int cur = kt & 1;
        if (kt + 1 < 16) stage(cur ^ 1);
        short8 af[2][2], bfr[4][2];
#pragma unroll
        for (int mf = 0; mf < 2; ++mf) {
            int r = wm * 32 + mf * 16 + row16;
#pragma unroll
            for (int kk = 0; kk < 2; ++kk)
                af[mf][kk] = *(const short8*)&As[cur][(r * 8 + ((kk * 4 + kgrp) ^ (r & 7))) * 8];
        }
#pragma unroll
        for (int nf = 0; nf < 4; ++nf) {
            int r = wn * 64 + nf * 16 + row16;
#pragma unroll
            for (int kk = 0; kk < 2; ++kk)
                bfr[nf][kk] = *(const short8*)&Bs[cur][(r * 8 + ((kk * 4 + kgrp) ^ (r & 7))) * 8];
        }
        __builtin_amdgcn_s_setprio(1);
#pragma unroll
        for (int kk = 0; kk < 2; ++kk)
#pragma unroll
            for (int mf = 0; mf < 2; ++mf)
#pragma unroll
                for (int nf = 0; nf < 4; ++nf)
                    acc[mf][nf] = __builtin_amdgcn_mfma_f32_16x16x32_bf16(af[mf][kk], bfr[nf][kk], acc[mf][nf], 0, 0, 0);
        __builtin_amdgcn_s_setprio(0);
        __syncthreads();
    }

    // fused epilogue
#pragma unroll
    for (int mf = 0; mf < 2; ++mf)
#pragma unroll
        for (int r = 0; r < 4; ++r) {
            int m = bm * 64 + wm * 32 + mf * 16 + kgrp * 4 + r;
            int s = m & 2047, bb = m >> 11;
            float v0 = acc[mf][0][r], v1 = acc[mf][1][r], v2 = acc[mf][2][r], v3 = acc[mf][3][r];
            if (bn < 10) {
                float c0 = cosb[s * 64 + row16],       c1 = cosb[s * 64 + 16 + row16];
                float n0 = sinb[s * 64 + row16],       n1 = sinb[s * 64 + 16 + row16];
                float o0 = v0 * c0 - v2 * n0, o1 = v1 * c1 - v3 * n1;
                float o2 = v2 * c0 + v0 * n0, o3 = v3 * c1 + v1 * n1;
                u16* dst;
                if (bn < 8) {
                    int h = bn * 2 + wn;
                    dst = Qa + ((size_t)(bb * 16 + h) * 2048 + s) * 64;
                    // fold 1/sqrt(64) * log2(e)
                    o0 *= 0.18033688f; o1 *= 0.18033688f; o2 *= 0.18033688f; o3 *= 0.18033688f;
                } else {
                    int kh = (bn - 8) * 2 + wn;
                    dst = Ka + ((size_t)(bb * 4 + kh) * 2048 + s) * 64;
                }
                dst[row16]      = f2b(o0);
                dst[row16 + 16] = f2b(o1);
                dst[row16 + 32] = f2b(o2);
                dst[row16 + 48] = f2b(o3);
            } else {
                u16* dst = Vtmp + (size_t)m * 256 + (bn - 10) * 128 + wn * 64;
                dst[row16]      = f2b(v0);
                dst[row16 + 16] = f2b(v1);
                dst[row16 + 32] = f2b(v2);
                dst[row16 + 48] = f2b(v3);
            }
        }
}

// ---------------- 3. V transpose: Vtmp[m][256] -> Vt[b][kh][d=64][s=2048] ----------------
__global__ __launch_bounds__(256) void vtrans_kernel(const u16* __restrict__ Vtmp, u16* __restrict__ Vt) {
    __shared__ u16 T[64 * 71];
    const int tid = threadIdx.x;
    const int sblk = blockIdx.x, kh = blockIdx.y, b = blockIdx.z;
    const u16* src = Vtmp + (size_t)(b * 2048 + sblk * 64) * 256 + kh * 64;
#pragma unroll
    for (int it = 0; it < 2; ++it) {
        int u = it * 256 + tid;
        int s = u >> 3, c = u & 7;
        short8 v = *(const short8*)(src + (size_t)s * 256 + c * 8);
#pragma unroll
        for (int i = 0; i < 8; ++i)
            T[(c * 8 + i) * 71 + s] = (u16)v[i];
    }
    __syncthreads();
    u16* dst = Vt + (size_t)(b * 4 + kh) * 64 * 2048 + sblk * 64;
#pragma unroll
    for (int it = 0; it < 2; ++it) {
        int u = it * 256 + tid;
        int d = u >> 3, s0 = (u & 7) * 8;
        short8 o;
#pragma unroll
        for (int i = 0; i < 8; ++i) o[i] = (short)T[d * 71 + s0 + i];
        *(short8*)(dst + (size_t)d * 2048 + s0) = o;
    }
}

// ---------------- 4. Flash attention: transposed LDS + reg-staged async split (T14) --------
// LDS layout: chunk(c,row) stored at index c*64 + (row^c)  (16B chunks).
//   - fragment reads: 16 consecutive lanes read contiguous LDS -> structural-minimum cycles
//   - staging: coalesced global reg-loads issued 1 tile ahead, ds_write after next barrier
// One raw s_barrier per iter; global loads NEVER drained at barriers (only lgkmcnt).
__global__ __launch_bounds__(256, 2) void attn_kernel(const u16* __restrict__ Qa,
                                                      const u16* __restrict__ Ka,
                                                      const u16* __restrict__ Vt,
                                                      u16* __restrict__ Ob) {
    __shared__ u16 Ks[2][4096];
    __shared__ u16 Vs[2][4096];
    const int tid = threadIdx.x, lane = tid & 63, wave = tid >> 6;
    const int q32 = lane & 31, hi = lane >> 5;
    const int qt = blockIdx.x, h = blockIdx.y, b = blockIdx.z;
    const int kh = h >> 2;
    const u16* Qp = Qa + ((size_t)(b * 16 + h) * 2048 + qt * 128 + wave * 32) * 64;

    // staging: thread loads rows (tid>>3, +32) chunk (tid&7) of each tile — coalesced
    const int lrow = tid >> 3, lc = tid & 7;
    const u16* kSrc = Ka + (size_t)(b * 4 + kh) * 2048 * 64 + (size_t)lrow * 64 + lc * 8;
    const u16* vSrc = Vt + (size_t)(b * 4 + kh) * 64 * 2048 + (size_t)lrow * 2048 + lc * 8;
    const int wk = (lc * 64 + (lrow ^ lc)) * 8;   // +256 for row+32

    // hoisted fragment-read offsets: rb[c] = chunk(c, q32)
    int rb[8];
#pragma unroll
    for (int c = 0; c < 8; ++c) rb[c] = (c * 64 + (q32 ^ c)) * 8;

    short8 qf[4];
#pragma unroll
    for (int dt = 0; dt < 4; ++dt)
        qf[dt] = *(const short8*)(Qp + q32 * 64 + dt * 16 + hi * 8);

    f32x16 oacc[2];
#pragma unroll
    for (int i = 0; i < 2; ++i)
#pragma unroll
        for (int r = 0; r < 16; ++r) oacc[i][r] = 0.f;
    float lpx = 0.f, lpy = 0.f;

    short8 kr0, kr1, vr0, vr1;
    auto LOAD = [&]() {
        kr0 = *(const short8*)kSrc;
        kr1 = *(const short8*)(kSrc + 2048);      // +32 rows
        vr0 = *(const short8*)vSrc;
        vr1 = *(const short8*)(vSrc + 65536);     // +32 d-rows
        kSrc += 4096; vSrc += 64;
    };
    auto WRITE = [&](int buf) {
        *(short8*)&Ks[buf][wk]       = kr0;
        *(short8*)&Ks[buf][wk + 256] = kr1;
        *(short8*)&Vs[buf][wk]       = vr0;
        *(short8*)&Vs[buf][wk + 256] = vr1;
    };

    LOAD();          // tile 0
    WRITE(0);        // compiler inserts precise vmcnt wait
    LOAD();          // tile 1 (stays in regs until next iter)
    asm volatile("s_waitcnt lgkmcnt(0)\n\ts_barrier" ::: "memory");

    for (int kvt = 0; kvt < 32; ++kvt) {
        const int cur = kvt & 1;
        if (kvt + 1 < 32) WRITE(cur ^ 1);   // tile kvt+1 into buffer freed by last barrier
        if (kvt + 2 < 32) LOAD();           // tile kvt+2 in flight across this compute

        // S^T = K_tile x Q^T : C[k'][q]
        f32x16 S[2];
#pragma unroll
        for (int j = 0; j < 2; ++j)
#pragma unroll
            for (int r = 0; r < 16; ++r) S[j][r] = 0.f;
        __builtin_amdgcn_s_setprio(1);
#pragma unroll
        for (int kt2 = 0; kt2 < 2; ++kt2) {
#pragma unroll
            for (int dt = 0; dt < 4; ++dt) {
                short8 kf = *(const short8*)&Ks[cur][rb[dt * 2 + hi] + kt2 * 256];
                S[kt2] = __builtin_amdgcn_mfma_f32_32x32x16_bf16(kf, qf[dt], S[kt2], 0, 0, 0);
            }
        }
        __builtin_amdgcn_s_setprio(0);

        // p = 2^s (log2e folded into Q scale); dual sum chains
#pragma unroll
        for (int kt2 = 0; kt2 < 2; ++kt2)
#pragma unroll
            for (int r = 0; r < 16; r += 2) {
                float p0 = fexp2(S[kt2][r]);
                float p1 = fexp2(S[kt2][r + 1]);
                S[kt2][r] = p0; S[kt2][r + 1] = p1;
                lpx += p0; lpy += p1;
            }

        // P -> bf16 B-frags (cvt_pk + permlane32_swap), O^T += V^T P^T
        __builtin_amdgcn_s_setprio(1);
#pragma unroll
        for (int kc = 0; kc < 4; ++kc) {
            const int kt2 = kc >> 1, R = (kc & 1) * 8;
            u32 a0 = cvtpk(S[kt2][R + 0], S[kt2][R + 1]);
            u32 b0 = cvtpk(S[kt2][R + 4], S[kt2][R + 5]);
            asm("v_permlane32_swap_b32 %0, %1" : "+v"(a0), "+v"(b0));
            u32 a1 = cvtpk(S[kt2][R + 2], S[kt2][R + 3]);
            u32 b1 = cvtpk(S[kt2][R + 6], S[kt2][R + 7]);
            asm("v_permlane32_swap_b32 %0, %1" : "+v"(a1), "+v"(b1));
            u32x4 pw; pw[0] = a0; pw[1] = a1; pw[2] = b0; pw[3] = b1;
            short8 pf = __builtin_bit_cast(short8, pw);
#pragma unroll
            for (int dt2 = 0; dt2 < 2; ++dt2) {
                short8 vf = *(const short8*)&Vs[cur][rb[kc * 2 + hi] + dt2 * 256];
                oacc[dt2] = __builtin_amdgcn_mfma_f32_32x32x16_bf16(vf, pf, oacc[dt2], 0, 0, 0);
            }
        }
        __builtin_amdgcn_s_setprio(0);

        // my reads of buf[cur] + my writes of buf[cur^1] complete; then all waves sync.
        asm volatile("s_waitcnt lgkmcnt(0)\n\ts_barrier" ::: "memory");
    }

    float lpart = lpx + lpy;
    float l = lpart + __shfl_xor(lpart, 32);
    float inv = 1.f / l;
    const size_t mbase = ((size_t)(b * 2048 + qt * 128 + wave * 32 + q32)) * 1024 + h * 64;
#pragma unroll
    for (int dt2 = 0; dt2 < 2; ++dt2)
#pragma unroll
        for (int rq = 0; rq < 4; ++rq) {
            ushort4 o;
            o.x = f2b(oacc[dt2][rq * 4 + 0] * inv);
            o.y = f2b(oacc[dt2][rq * 4 + 1] * inv);
            o.z = f2b(oacc[dt2][rq * 4 + 2] * inv);
            o.w = f2b(oacc[dt2][rq * 4 + 3] * inv);
            *(ushort4*)&Ob[mbase + dt2 * 32 + rq * 8 + hi * 4] = o;
        }
}

// ---------------- 5. Out-proj GEMM (unchanged structure) ----------------
template <typename OUT>
__global__ __launch_bounds__(256, 3) void gemm_bt(const u16* __restrict__ A, const u16* __restrict__ B,
                                                  OUT* __restrict__ C, int M, int N, int K) {
    __shared__ u16 As[2][64 * 64];
    __shared__ u16 Bs[2][128 * 64];
    const int tid = threadIdx.x;
    const int lane = tid & 63, wave = tid >> 6;
    const int wm = wave >> 1, wn = wave & 1;
    const int row16 = lane & 15, kgrp = lane >> 4;
    const int bm = blockIdx.x, bn = blockIdx.y;
    const int nk = K >> 6;

    const int r0 = tid >> 3, c0s = ((tid & 7) ^ (r0 & 7)) * 8;
    const u16* aSrc = A + (size_t)(bm * 64 + r0) * K + c0s;
    const u16* bSrc = B + (size_t)(bn * 128 + r0) * K + c0s;
    u16* const ad0 = &As[0][tid * 8];
    u16* const ad1 = &As[0][(tid + 256) * 8];
    u16* const bd0 = &Bs[0][tid * 8];
    u16* const bd1 = &Bs[0][(tid + 256) * 8];
    u16* const bd2 = &Bs[0][(tid + 512) * 8];
    u16* const bd3 = &Bs[0][(tid + 768) * 8];
    const size_t aK32 = (size_t)32 * K;

    f32x4 acc[2][4];
#pragma unroll
    for (int i = 0; i < 2; ++i)
#pragma unroll
        for (int j = 0; j < 4; ++j) acc[i][j] = {0.f, 0.f, 0.f, 0.f};

    auto stage = [&](int buf) {
        int lo = buf * 4096;
        int lob = buf * 8192;
        gload16(aSrc, ad0 + lo);
        gload16(aSrc + aK32, ad1 + lo);
        gload16(bSrc, bd0 + lob);
        gload16(bSrc + aK32, bd1 + lob);
        gload16(bSrc + 2 * aK32, bd2 + lob);
        gload16(bSrc + 3 * aK32, bd3 + lob);
        aSrc += 64; bSrc += 64;
    };

    stage(0);
    __syncthreads();
    for (int kt = 0; kt < nk; ++kt) {
        int cur = kt & 1;
        if (kt + 1 < nk) stage(cur ^ 1);
        short8 af[2][2], bfr[4][2];
#pragma unroll
        for (int mf = 0; mf < 2; ++mf) {
            int r = wm * 32 + mf * 16 + row16;
#pragma unroll
            for (int kk = 0; kk < 2; ++kk)
                af[mf][kk] = *(const short8*)&As[cur][(r * 8 + ((kk * 4 + kgrp) ^ (r & 7))) * 8];
        }
#pragma unroll
        for (int nf = 0; nf < 4; ++nf) {
            int r = wn * 64 + nf * 16 + row16;
#pragma unroll
            for (int kk = 0; kk < 2; ++kk)
                bfr[nf][kk] = *(const short8*)&Bs[cur][(r * 8 + ((kk * 4 + kgrp) ^ (r & 7))) * 8];
        }
        __builtin_amdgcn_s_setprio(1);
#pragma unroll
        for (int kk = 0; kk < 2; ++kk)
#pragma unroll
            for (int mf = 0; mf < 2; ++mf)
#pragma unroll
                for (int nf = 0; nf < 4; ++nf)
                    acc[mf][nf] = __builtin_amdgcn_mfma_f32_16x16x32_bf16(af[mf][kk], bfr[nf][kk], acc[mf][nf], 0, 0, 0);
        __builtin_amdgcn_s_setprio(0);
        __syncthreads();
    }
#pragma unroll
    for (int mf = 0; mf < 2; ++mf)
#pragma unroll
        for (int r = 0; r < 4; ++r) {
            int row = bm * 64 + wm * 32 + mf * 16 + kgrp * 4 + r;
#pragma unroll
            for (int nf = 0; nf < 4; ++nf) {
                int col = bn * 128 + wn * 64 + nf * 16 + row16;
                float v = acc[mf][nf][r];
                if constexpr (sizeof(OUT) == 2) C[(size_t)row * N + col] = f2b(v);
                else                            C[(size_t)row * N + col] = v;
            }
        }
}

// ---------------- launcher ----------------
extern "C" void kernel_launch(void* const* d_in, const int* in_sizes, int n_in,
                              void* d_out, int out_size, void* d_ws, size_t ws_size,
                              hipStream_t stream) {
    const float* X    = (const float*)d_in[0];
    const float* cosb = (const float*)d_in[1];
    const float* sinb = (const float*)d_in[2];
    const float* Wqkv = (const float*)d_in[3];
    const float* Wo   = (const float*)d_in[4];
    float* out = (float*)d_out;
    char* ws = (char*)d_ws;

    u16* Xbf    = (u16*)(ws);                    // 8,388,608 B (aliased attnb after gemm1)
    u16* Wqkvbf = (u16*)(ws + 8388608);          // 3,145,728 B
    u16* Wobf   = (u16*)(ws + 11534336);         // 2,097,152 B
    u16* Vtmp   = (u16*)(ws + 13631488);         // 2,097,152 B
    u16* Qa     = (u16*)(ws + 26214400);         // 8,388,608 B
    u16* Ka     = (u16*)(ws + 34603008);         // 2,097,152 B
    u16* Vt     = (u16*)(ws + 36700160);         // 2,097,152 B -> total 38,797,312 B
    u16* attnb  = Xbf;

    convert_kernel<<<6656, 256, 0, stream>>>(X, Wqkv, Wo, Xbf, Wqkvbf, Wobf);
    gemm_qkv<<<dim3(64, 12), 256, 0, stream>>>(Xbf, Wqkvbf, cosb, sinb, Qa, Ka, Vtmp);
    vtrans_kernel<<<dim3(32, 4, 2), 256, 0, stream>>>(Vtmp, Vt);
    attn_kernel<<<dim3(16, 16, 2), 256, 0, stream>>>(Qa, Ka, Vt, attnb);
    gemm_bt<float><<<dim3(64, 8), 256, 0, stream>>>(attnb, Wobf, out, 4096, 1024, 1024);
}